// Round 10
// baseline (541.696 us; speedup 1.0000x reference)
//
#include <hip/hip_runtime.h>
#include <math.h>

__device__ __forceinline__ float silu(float x) { return x / (1.0f + __expf(-x)); }

// ---------------- Kernel 1: per-node precompute, 8 nodes/block -------------
__global__ __launch_bounds__(320) void node_pre_kernel(
    const float* __restrict__ nf, const float* __restrict__ na,
    const float* __restrict__ w0, const float* __restrict__ w1,
    const float* __restrict__ scw0, const float* __restrict__ scw1,
    float* __restrict__ y, float* __restrict__ sc, int N)
{
  __shared__ float sW0[1024];   // lin1_w0 [32][32]
  __shared__ float sW1[1024];   // lin1_w1 [32][32]
  __shared__ float sS0[8192];   // sc_w0 [128][64]
  __shared__ float sS1[4096];   // sc_w1 [128][32]
  __shared__ float snf[128];
  __shared__ float sna4[4];
  const int t = threadIdx.x;
  for (int x = t; x < 1024; x += 320) sW0[x] = w0[x];
  for (int x = t; x < 1024; x += 320) sW1[x] = w1[x];
  for (int x = t; x < 8192; x += 320) sS0[x] = scw0[x];
  for (int x = t; x < 4096; x += 320) sS1[x] = scw1[x];

  const float inv_sqrt32 = 0.17677669529663687f;
  const float sc_norm    = 0.08838834764831843f;  // 1/sqrt(32*4)
  const int node0 = blockIdx.x * 8;

  for (int nn = 0; nn < 8; ++nn) {
    const int n = node0 + nn;
    if (n >= N) break;
    __syncthreads();   // weights ready (iter 0) / previous iter's readers done
    if (t < 128) snf[t] = nf[(size_t)n * 128 + t];
    else if (t < 132) sna4[t - 128] = na[(size_t)n * 4 + (t - 128)];
    __syncthreads();

    if (t < 32) {
      const int w = t;
      float acc = 0.f;
      for (int u = 0; u < 32; ++u) acc += snf[u] * sW0[u * 32 + w];
      y[(size_t)n * 128 + w] = acc * inv_sqrt32;
    } else if (t < 128) {
      const int q = t - 32, w = q / 3, i = q - w * 3;
      float acc = 0.f;
      for (int u = 0; u < 32; ++u) acc += snf[32 + u * 3 + i] * sW1[u * 32 + w];
      y[(size_t)n * 128 + 32 + w * 3 + i] = acc * inv_sqrt32;
    } else if (t < 192) {
      const int w = t - 128;
      float acc = 0.f;
      for (int k = 0; k < 128; ++k) acc += snf[k >> 2] * sna4[k & 3] * sS0[k * 64 + w];
      sc[(size_t)n * 160 + w] = acc * sc_norm;
    } else if (t < 288) {
      const int q = t - 192, w = q / 3, i = q - w * 3;
      float acc = 0.f;
      for (int k = 0; k < 128; ++k) acc += snf[32 + (k >> 2) * 3 + i] * sna4[k & 3] * sS1[k * 32 + w];
      sc[(size_t)n * 160 + 64 + w * 3 + i] = acc * sc_norm;
    }
  }
}

// ---------------- CSR build (unchanged) ----------------
__global__ __launch_bounds__(256) void hist_kernel(const int* __restrict__ eidx,
                                                   int* __restrict__ counts, int E)
{
  const int e = blockIdx.x * 256 + threadIdx.x;
  if (e < E) atomicAdd(&counts[eidx[E + e]], 1);
}

__global__ __launch_bounds__(1024) void scan_kernel(const int* __restrict__ counts,
                                                    int* __restrict__ offsets,
                                                    int* __restrict__ cursor, int N)
{
  __shared__ int part[1024];
  const int t = threadIdx.x;
  const int per = (N + 1023) / 1024;
  const int base = t * per;
  int s = 0;
  for (int k = 0; k < per; ++k) { int idx = base + k; if (idx < N) s += counts[idx]; }
  part[t] = s;
  __syncthreads();
  for (int off = 1; off < 1024; off <<= 1) {
    int v = part[t];
    if (t >= off) v += part[t - off];
    __syncthreads();
    part[t] = v;
    __syncthreads();
  }
  int run = (t == 0) ? 0 : part[t - 1];
  for (int k = 0; k < per; ++k) {
    int idx = base + k;
    if (idx < N) { offsets[idx] = run; cursor[idx] = run; run += counts[idx]; }
  }
  if (t == 1023) offsets[N] = run;
}

__global__ __launch_bounds__(256) void scatter_kernel(const int* __restrict__ eidx,
                                                      int* __restrict__ cursor,
                                                      int* __restrict__ elist, int E)
{
  const int e = blockIdx.x * 256 + threadIdx.x;
  if (e >= E) return;
  const int dst = eidx[E + e];
  const int slot = atomicAdd(&cursor[dst], 1);
  elist[slot] = e;
}

// ---------------- Kernel 2: FUSED 3-layer edge MLP (tile = 128 edges) ------
// LDS 50KB -> 3 blocks/CU. w3 read directly from global (L1-resident 32KB).
__global__ __launch_bounds__(256, 3) void edge_mlp_kernel(
    const float* __restrict__ eemb, const float* __restrict__ fw1,
    const float* __restrict__ fw2, const float* __restrict__ fw3,
    const int* __restrict__ elist, float* __restrict__ wbuf, int E)
{
  __shared__ __align__(16) float w1L[512];    // [k<64][r<8] transposed
  __shared__ __align__(16) float w2L[4096];   // w2 [64][64]
  __shared__ __align__(16) float hL[8192];    // A/B: h1[k][e] ; C: h2[k][e]
  const int t = threadIdx.x;
  const int base = blockIdx.x * 128;

  for (int x = t; x < 512; x += 256)  w1L[x] = fw1[(x & 7) * 64 + (x >> 3)];
  for (int x = t; x < 4096; x += 256) w2L[x] = fw2[x];

  // per-thread edge (2 threads per edge), emb kept in registers
  const int e = t & 127, kg = t >> 7;
  const int slot0 = base + e;
  const int eid = (slot0 < E) ? elist[slot0] : 0;
  const float4 em0 = *(const float4*)(eemb + (size_t)eid * 8);
  const float4 em1 = *(const float4*)(eemb + (size_t)eid * 8 + 4);
  __syncthreads();

  {  // ---- phase A: h1[k][e], 32 k per thread ----
    const float inv_sqrt8 = 0.35355339059327373f;
#pragma unroll
    for (int kk = 0; kk < 32; ++kk) {
      const int k = kg * 32 + kk;
      const float4 wa = *(const float4*)(w1L + k * 8);
      const float4 wb = *(const float4*)(w1L + k * 8 + 4);
      const float a = em0.x * wa.x + em0.y * wa.y + em0.z * wa.z + em0.w * wa.w
                    + em1.x * wb.x + em1.y * wb.y + em1.z * wb.z + em1.w * wb.w;
      hL[k * 128 + e] = silu(a * inv_sqrt8);
    }
  }
  __syncthreads();

  const int og = t & 7, eg = t >> 3;
  const int e0 = eg * 4;

  // ---- phase B: h2 micro-tile 4e x 8o into registers ----
  float acc[4][8];
#pragma unroll
  for (int i = 0; i < 4; ++i)
#pragma unroll
    for (int j = 0; j < 8; ++j) acc[i][j] = 0.f;
  {
    const int o0 = og * 8;
#pragma unroll 2
    for (int k = 0; k < 64; ++k) {
      const float4 hv  = *(const float4*)(hL + k * 128 + e0);
      const float4 w0v = *(const float4*)(w2L + k * 64 + o0);
      const float4 w1v = *(const float4*)(w2L + k * 64 + o0 + 4);
      const float h[4] = {hv.x, hv.y, hv.z, hv.w};
      const float w[8] = {w0v.x, w0v.y, w0v.z, w0v.w, w1v.x, w1v.y, w1v.z, w1v.w};
#pragma unroll
      for (int i = 0; i < 4; ++i)
#pragma unroll
        for (int j = 0; j < 8; ++j) acc[i][j] += h[i] * w[j];
    }
  }
  __syncthreads();   // all hL(h1)/w2L reads complete

  // ---- handoff: h2 regs -> hL rows (b128 rows: conflict-optimal) ----
#pragma unroll
  for (int j = 0; j < 8; ++j) {
    const int k = og * 8 + j;
    float4 v;
    v.x = silu(acc[0][j] * 0.125f);
    v.y = silu(acc[1][j] * 0.125f);
    v.z = silu(acc[2][j] * 0.125f);
    v.w = silu(acc[3][j] * 0.125f);
    *(float4*)(hL + k * 128 + e0) = v;
  }
  __syncthreads();

  // ---- phase C: layer 3 micro-tile 4e x 16c; w3 straight from global/L1 ----
  const int c0 = og * 16;
  float accw[4][16];
#pragma unroll
  for (int i = 0; i < 4; ++i)
#pragma unroll
    for (int j = 0; j < 16; ++j) accw[i][j] = 0.f;

#pragma unroll 2
  for (int k = 0; k < 64; ++k) {
    const float4 hv = *(const float4*)(hL + k * 128 + e0);
    const float h[4] = {hv.x, hv.y, hv.z, hv.w};
    float w[16];
#pragma unroll
    for (int j = 0; j < 4; ++j) {
      const float4 wv = *(const float4*)(fw3 + k * 128 + c0 + j * 4);
      w[j * 4] = wv.x; w[j * 4 + 1] = wv.y; w[j * 4 + 2] = wv.z; w[j * 4 + 3] = wv.w;
    }
#pragma unroll
    for (int i = 0; i < 4; ++i)
#pragma unroll
      for (int j = 0; j < 16; ++j) accw[i][j] += h[i] * w[j];
  }
#pragma unroll
  for (int i = 0; i < 4; ++i) {
    const int slot = base + e0 + i;
    if (slot < E) {
#pragma unroll
      for (int j = 0; j < 16; j += 4) {
        float4 v;
        v.x = accw[i][j] * 0.125f;     v.y = accw[i][j + 1] * 0.125f;
        v.z = accw[i][j + 2] * 0.125f; v.w = accw[i][j + 3] * 0.125f;
        *(float4*)(wbuf + (size_t)slot * 128 + c0 + j) = v;
      }
    }
  }
}

// ---------------- Kernel 3: 1 node/block, chunked cooperative staging ------
__global__ __launch_bounds__(256) void gather_out_kernel(
    const float* __restrict__ nf, const float* __restrict__ wbuf,
    const float* __restrict__ y, const float* __restrict__ sc,
    const float* __restrict__ l2w0, const float* __restrict__ l2w1,
    const int* __restrict__ offsets, const int* __restrict__ elist,
    const int* __restrict__ eidx, const float* __restrict__ eattr,
    const int* __restrict__ avgp, float* __restrict__ out, int N, int E)
{
  constexpr int CH = 32;
  __shared__ int sSrc[CH];
  __shared__ __align__(16) float eaL[CH][4];
  __shared__ __align__(16) float yL[CH][128];
  __shared__ float sm[256];
  __shared__ float so0[64];
  __shared__ float so1[96];
  const int n = blockIdx.x, t = threadIdx.x;

  int wi, yi0, yi1, yi2, selA;  // selA: 0=e0,1=e1x,2=e1y,3=e1z
  bool is1 = false;
  if (t < 32) {            // o_s0[u]
    wi = t; yi0 = yi1 = yi2 = t; selA = 0;
  } else if (t < 64) {     // o_s1[u]
    const int u = t - 32;
    wi = 96 + u; yi0 = 32 + 3 * u; yi1 = yi0 + 1; yi2 = yi0 + 2; selA = 1; is1 = true;
  } else if (t < 160) {    // o_v0[u][i]
    const int q = t - 64, u = q / 3, i = q - u * 3;
    wi = 32 + u; yi0 = yi1 = yi2 = u; selA = 1 + i;
  } else {                 // o_v1[u][i]
    const int q = t - 160, u = q / 3, i = q - u * 3;
    wi = 64 + u; yi0 = yi1 = yi2 = 32 + 3 * u + i; selA = 0;
  }

  const int beg = offsets[n], end = offsets[n + 1];
  float accv = 0.f;

  for (int c0 = beg; c0 < end; c0 += CH) {
    const int cn = min(CH, end - c0);
    if (t < CH) {
      int srcv = 0;
      float4 eav = make_float4(0.f, 0.f, 0.f, 0.f);
      if (t < cn) {
        const int eid = elist[c0 + t];
        srcv = eidx[eid];
        eav = *(const float4*)(eattr + (size_t)eid * 4);
      }
      sSrc[t] = srcv;
      *(float4*)&eaL[t][0] = eav;
    }
    __syncthreads();
#pragma unroll
    for (int p = 0; p < 4; ++p) {
      const int lin = p * 256 + t;          // float4 index
      const int row = lin >> 5, f4 = lin & 31;
      if (row < cn) {
        *(float4*)&yL[row][f4 * 4] =
            *(const float4*)(y + (size_t)sSrc[row] * 128 + f4 * 4);
      }
    }
    __syncthreads();
    for (int i0 = 0; i0 < cn; i0 += 4) {
      float wq[4];
#pragma unroll
      for (int q = 0; q < 4; ++q) {
        const int i = i0 + q;
        wq[q] = (i < cn) ? wbuf[(size_t)(c0 + i) * 128 + wi] : 0.f;
      }
#pragma unroll
      for (int q = 0; q < 4; ++q) {
        const int i = i0 + q;
        if (i < cn) {
          const float* yr = yL[i];
          const float A = eaL[i][selA];
          if (is1) {
            accv += wq[q] * (A * yr[yi0] + eaL[i][2] * yr[yi1] + eaL[i][3] * yr[yi2]);
          } else {
            accv += wq[q] * (A * yr[yi0]);
          }
        }
      }
    }
    __syncthreads();   // protect yL before next chunk overwrites
  }

  const float inv_sqrt3 = 0.5773502691896258f;
  if (is1) accv *= inv_sqrt3;
  sm[t] = accv;
  __syncthreads();

  const float inv_avg = rsqrtf((float)(*avgp));
  const float scl = 0.125f * inv_avg;
  if (t < 64) {
    float acc = 0.f;
    for (int u = 0; u < 64; ++u) acc += sm[u] * l2w0[u * 64 + t];
    so0[t] = acc * scl + sc[(size_t)n * 160 + t];
  } else if (t < 160) {
    const int q = t - 64, w = q / 3, i = q - w * 3;
    float acc = 0.f;
    for (int u = 0; u < 64; ++u) acc += sm[64 + u * 3 + i] * l2w1[u * 32 + w];
    so1[w * 3 + i] = acc * scl + sc[(size_t)n * 160 + 64 + w * 3 + i];
  }
  __syncthreads();
  if (t < 32) {
    out[(size_t)n * 128 + t] = nf[(size_t)n * 128 + t] + silu(so0[t]);
  } else if (t < 128) {
    const int q = t - 32, w = q / 3, i = q - w * 3;
    out[(size_t)n * 128 + t] = nf[(size_t)n * 128 + t] + silu(so0[32 + w]) * so1[w * 3 + i];
  }
}

extern "C" void kernel_launch(void* const* d_in, const int* in_sizes, int n_in,
                              void* d_out, int out_size, void* d_ws, size_t ws_size,
                              hipStream_t stream)
{
  const float* nf    = (const float*)d_in[0];
  const float* na    = (const float*)d_in[1];
  const float* eattr = (const float*)d_in[2];
  const float* eemb  = (const float*)d_in[3];
  const float* l1w0  = (const float*)d_in[4];
  const float* l1w1  = (const float*)d_in[5];
  const float* fw1   = (const float*)d_in[6];
  const float* fw2   = (const float*)d_in[7];
  const float* fw3   = (const float*)d_in[8];
  const float* l2w0  = (const float*)d_in[9];
  const float* l2w1  = (const float*)d_in[10];
  const float* scw0  = (const float*)d_in[11];
  const float* scw1  = (const float*)d_in[12];
  const int*   eidx  = (const int*)d_in[13];
  const int*   avgp  = (const int*)d_in[14];

  const int N = in_sizes[0] / 128;
  const int E = in_sizes[2] / 4;

  // Same byte layout as R3-R9 (known to fit in ws_size).
  float* y       = (float*)d_ws;                    // N*128
  float* sc      = y + (size_t)N * 128;             // N*160
  float* wbuf    = sc + (size_t)N * 160;            // E*128 (slot-major, sorted by dst)
  int*   counts  = (int*)(wbuf + (size_t)E * 128);  // N
  int*   offsets = counts + N;                      // N+1
  int*   cursor  = offsets + N + 1;                 // N
  int*   elist   = cursor + N;                      // E (slot -> eid)

  hipMemsetAsync(counts, 0, (size_t)N * sizeof(int), stream);
  node_pre_kernel<<<(N + 7) / 8, 320, 0, stream>>>(nf, na, l1w0, l1w1, scw0, scw1, y, sc, N);
  hist_kernel<<<(E + 255) / 256, 256, 0, stream>>>(eidx, counts, E);
  scan_kernel<<<1, 1024, 0, stream>>>(counts, offsets, cursor, N);
  scatter_kernel<<<(E + 255) / 256, 256, 0, stream>>>(eidx, cursor, elist, E);
  edge_mlp_kernel<<<(E + 127) / 128, 256, 0, stream>>>(eemb, fw1, fw2, fw3, elist, wbuf, E);
  gather_out_kernel<<<N, 256, 0, stream>>>(nf, wbuf, y, sc, l2w0, l2w1,
                                           offsets, elist, eidx, eattr, avgp,
                                           (float*)d_out, N, E);
}

// Round 11
// 383.643 us; speedup vs baseline: 1.4120x; 1.4120x over previous
//
#include <hip/hip_runtime.h>
#include <math.h>

__device__ __forceinline__ float silu(float x) { return x / (1.0f + __expf(-x)); }

// ---------------- Kernel 1: per-node precompute (R9 version) ---------------
__global__ __launch_bounds__(320) void node_pre_kernel(
    const float* __restrict__ nf, const float* __restrict__ na,
    const float* __restrict__ w0, const float* __restrict__ w1,
    const float* __restrict__ scw0, const float* __restrict__ scw1,
    float* __restrict__ y, float* __restrict__ sc)
{
  __shared__ float snf[128];
  __shared__ float sna[4];
  const int n = blockIdx.x;
  const int t = threadIdx.x;
  if (t < 128) snf[t] = nf[n * 128 + t];
  if (t >= 128 && t < 132) sna[t - 128] = na[n * 4 + (t - 128)];
  __syncthreads();
  const float inv_sqrt32 = 0.17677669529663687f;
  const float sc_norm    = 0.08838834764831843f;  // 1/sqrt(32*4)
  if (t < 32) {
    const int w = t;
    float acc = 0.f;
    for (int u = 0; u < 32; ++u) acc += snf[u] * w0[u * 32 + w];
    y[n * 128 + w] = acc * inv_sqrt32;
  } else if (t < 128) {
    const int q = t - 32, w = q / 3, i = q - w * 3;
    float acc = 0.f;
    for (int u = 0; u < 32; ++u) acc += snf[32 + u * 3 + i] * w1[u * 32 + w];
    y[n * 128 + 32 + w * 3 + i] = acc * inv_sqrt32;
  } else if (t < 192) {
    const int w = t - 128;
    float acc = 0.f;
    for (int k = 0; k < 128; ++k) acc += snf[k >> 2] * sna[k & 3] * scw0[k * 64 + w];
    sc[n * 160 + w] = acc * sc_norm;
  } else if (t < 288) {
    const int q = t - 192, w = q / 3, i = q - w * 3;
    float acc = 0.f;
    for (int k = 0; k < 128; ++k) acc += snf[32 + (k >> 2) * 3 + i] * sna[k & 3] * scw1[k * 32 + w];
    sc[n * 160 + 64 + w * 3 + i] = acc * sc_norm;
  }
}

// ---------------- CSR build (unchanged) ----------------
__global__ __launch_bounds__(256) void hist_kernel(const int* __restrict__ eidx,
                                                   int* __restrict__ counts, int E)
{
  const int e = blockIdx.x * 256 + threadIdx.x;
  if (e < E) atomicAdd(&counts[eidx[E + e]], 1);
}

__global__ __launch_bounds__(1024) void scan_kernel(const int* __restrict__ counts,
                                                    int* __restrict__ offsets,
                                                    int* __restrict__ cursor, int N)
{
  __shared__ int part[1024];
  const int t = threadIdx.x;
  const int per = (N + 1023) / 1024;
  const int base = t * per;
  int s = 0;
  for (int k = 0; k < per; ++k) { int idx = base + k; if (idx < N) s += counts[idx]; }
  part[t] = s;
  __syncthreads();
  for (int off = 1; off < 1024; off <<= 1) {
    int v = part[t];
    if (t >= off) v += part[t - off];
    __syncthreads();
    part[t] = v;
    __syncthreads();
  }
  int run = (t == 0) ? 0 : part[t - 1];
  for (int k = 0; k < per; ++k) {
    int idx = base + k;
    if (idx < N) { offsets[idx] = run; cursor[idx] = run; run += counts[idx]; }
  }
  if (t == 1023) offsets[N] = run;
}

__global__ __launch_bounds__(256) void scatter_kernel(const int* __restrict__ eidx,
                                                      int* __restrict__ cursor,
                                                      int* __restrict__ elist, int E)
{
  const int e = blockIdx.x * 256 + threadIdx.x;
  if (e >= E) return;
  const int dst = eidx[E + e];
  const int slot = atomicAdd(&cursor[dst], 1);
  elist[slot] = e;
}

// ---------------- Kernel 2: FUSED 3-layer edge MLP (tile = 128 edges) ------
// R9 structure (w3 in LDS, swizzled stride 144); phase C retiled to 8e x 8c.
__global__ __launch_bounds__(256) void edge_mlp_kernel(
    const float* __restrict__ eemb, const float* __restrict__ fw1,
    const float* __restrict__ fw2, const float* __restrict__ fw3,
    const int* __restrict__ elist, float* __restrict__ wbuf, int E)
{
  __shared__ __align__(16) float w1L[512];    // [k<64][r<8] transposed
  __shared__ __align__(16) float reg2[9216];  // B: w2[64][64] ; C: w3 swz [64][144]
  __shared__ __align__(16) float hL[8192];    // A/B: h1[k][e] ; C: h2[k][e]
  const int t = threadIdx.x;
  const int base = blockIdx.x * 128;

  for (int x = t; x < 512; x += 256)  w1L[x] = fw1[(x & 7) * 64 + (x >> 3)];
  for (int x = t; x < 4096; x += 256) reg2[x] = fw2[x];

  // per-thread edge (2 threads per edge), emb kept in registers
  const int e = t & 127, kg = t >> 7;
  const int slot0 = base + e;
  const int eid = (slot0 < E) ? elist[slot0] : 0;
  const float4 em0 = *(const float4*)(eemb + (size_t)eid * 8);
  const float4 em1 = *(const float4*)(eemb + (size_t)eid * 8 + 4);
  __syncthreads();

  {  // ---- phase A: h1[k][e], 32 k per thread ----
    const float inv_sqrt8 = 0.35355339059327373f;
#pragma unroll
    for (int kk = 0; kk < 32; ++kk) {
      const int k = kg * 32 + kk;
      const float4 wa = *(const float4*)(w1L + k * 8);
      const float4 wb = *(const float4*)(w1L + k * 8 + 4);
      const float a = em0.x * wa.x + em0.y * wa.y + em0.z * wa.z + em0.w * wa.w
                    + em1.x * wb.x + em1.y * wb.y + em1.z * wb.z + em1.w * wb.w;
      hL[k * 128 + e] = silu(a * inv_sqrt8);
    }
  }
  __syncthreads();

  const int og = t & 7, eg = t >> 3;
  const int e0 = eg * 4;

  // ---- phase B: h2 micro-tile 4e x 8o into registers ----
  float acc[4][8];
#pragma unroll
  for (int i = 0; i < 4; ++i)
#pragma unroll
    for (int j = 0; j < 8; ++j) acc[i][j] = 0.f;
  {
    const int o0 = og * 8;
    for (int k = 0; k < 64; ++k) {
      const float4 hv  = *(const float4*)(hL + k * 128 + e0);
      const float4 w0v = *(const float4*)(reg2 + k * 64 + o0);
      const float4 w1v = *(const float4*)(reg2 + k * 64 + o0 + 4);
      const float h[4] = {hv.x, hv.y, hv.z, hv.w};
      const float w[8] = {w0v.x, w0v.y, w0v.z, w0v.w, w1v.x, w1v.y, w1v.z, w1v.w};
#pragma unroll
      for (int i = 0; i < 4; ++i)
#pragma unroll
        for (int j = 0; j < 8; ++j) acc[i][j] += h[i] * w[j];
    }
  }
  __syncthreads();   // all hL(h1)/reg2(w2) reads complete

  // ---- handoff: h2 regs -> hL rows (b128 rows: conflict-optimal) ----
#pragma unroll
  for (int j = 0; j < 8; ++j) {
    const int k = og * 8 + j;
    float4 v;
    v.x = silu(acc[0][j] * 0.125f);
    v.y = silu(acc[1][j] * 0.125f);
    v.z = silu(acc[2][j] * 0.125f);
    v.w = silu(acc[3][j] * 0.125f);
    *(float4*)(hL + k * 128 + e0) = v;
  }
  // ---- stage w3 swizzled into reg2 (stride 144, +((c>>5)<<2)) ----
  for (int x = t; x < 8192; x += 256) {
    const int k = x >> 7, c = x & 127;
    reg2[k * 144 + c + ((c >> 5) << 2)] = fw3[x];
  }
  __syncthreads();

  // ---- phase C: layer 3 micro-tile 8e x 8c (4 b128/k instead of 5) ----
  const int cg = t & 15, er = t >> 4;
  const int c0 = cg * 8, e0c = er * 8;
  const int cs = c0 + ((c0 >> 5) << 2);   // 8-col group stays inside one 32-col swz block
  float accw[8][8];
#pragma unroll
  for (int i = 0; i < 8; ++i)
#pragma unroll
    for (int j = 0; j < 8; ++j) accw[i][j] = 0.f;

  for (int k = 0; k < 64; ++k) {
    const float4 ha = *(const float4*)(hL + k * 128 + e0c);
    const float4 hb = *(const float4*)(hL + k * 128 + e0c + 4);
    const float4 wa = *(const float4*)(reg2 + k * 144 + cs);
    const float4 wb = *(const float4*)(reg2 + k * 144 + cs + 4);
    const float h[8] = {ha.x, ha.y, ha.z, ha.w, hb.x, hb.y, hb.z, hb.w};
    const float w[8] = {wa.x, wa.y, wa.z, wa.w, wb.x, wb.y, wb.z, wb.w};
#pragma unroll
    for (int i = 0; i < 8; ++i)
#pragma unroll
      for (int j = 0; j < 8; ++j) accw[i][j] += h[i] * w[j];
  }
#pragma unroll
  for (int i = 0; i < 8; ++i) {
    const int slot = base + e0c + i;
    if (slot < E) {
#pragma unroll
      for (int j = 0; j < 8; j += 4) {
        float4 v;
        v.x = accw[i][j] * 0.125f;     v.y = accw[i][j + 1] * 0.125f;
        v.z = accw[i][j + 2] * 0.125f; v.w = accw[i][j + 3] * 0.125f;
        *(float4*)(wbuf + (size_t)slot * 128 + c0 + j) = v;
      }
    }
  }
}

// ---------------- Kernel 3: 1 node/block, chunked cooperative staging ------
__global__ __launch_bounds__(256) void gather_out_kernel(
    const float* __restrict__ nf, const float* __restrict__ wbuf,
    const float* __restrict__ y, const float* __restrict__ sc,
    const float* __restrict__ l2w0, const float* __restrict__ l2w1,
    const int* __restrict__ offsets, const int* __restrict__ elist,
    const int* __restrict__ eidx, const float* __restrict__ eattr,
    const int* __restrict__ avgp, float* __restrict__ out, int N, int E)
{
  constexpr int CH = 32;
  __shared__ int sSrc[CH];
  __shared__ __align__(16) float eaL[CH][4];
  __shared__ __align__(16) float yL[CH][128];
  __shared__ float sm[256];
  __shared__ float so0[64];
  __shared__ float so1[96];
  const int n = blockIdx.x, t = threadIdx.x;

  int wi, yi0, yi1, yi2, selA;  // selA: 0=e0,1=e1x,2=e1y,3=e1z
  bool is1 = false;
  if (t < 32) {            // o_s0[u]
    wi = t; yi0 = yi1 = yi2 = t; selA = 0;
  } else if (t < 64) {     // o_s1[u]
    const int u = t - 32;
    wi = 96 + u; yi0 = 32 + 3 * u; yi1 = yi0 + 1; yi2 = yi0 + 2; selA = 1; is1 = true;
  } else if (t < 160) {    // o_v0[u][i]
    const int q = t - 64, u = q / 3, i = q - u * 3;
    wi = 32 + u; yi0 = yi1 = yi2 = u; selA = 1 + i;
  } else {                 // o_v1[u][i]
    const int q = t - 160, u = q / 3, i = q - u * 3;
    wi = 64 + u; yi0 = yi1 = yi2 = 32 + 3 * u + i; selA = 0;
  }

  const int beg = offsets[n], end = offsets[n + 1];
  float accv = 0.f;

  for (int c0 = beg; c0 < end; c0 += CH) {
    const int cn = min(CH, end - c0);
    if (t < CH) {
      int srcv = 0;
      float4 eav = make_float4(0.f, 0.f, 0.f, 0.f);
      if (t < cn) {
        const int eid = elist[c0 + t];
        srcv = eidx[eid];
        eav = *(const float4*)(eattr + (size_t)eid * 4);
      }
      sSrc[t] = srcv;
      *(float4*)&eaL[t][0] = eav;
    }
    __syncthreads();
#pragma unroll
    for (int p = 0; p < 4; ++p) {
      const int lin = p * 256 + t;          // float4 index
      const int row = lin >> 5, f4 = lin & 31;
      if (row < cn) {
        *(float4*)&yL[row][f4 * 4] =
            *(const float4*)(y + (size_t)sSrc[row] * 128 + f4 * 4);
      }
    }
    __syncthreads();
    for (int i0 = 0; i0 < cn; i0 += 4) {
      float wq[4];
#pragma unroll
      for (int q = 0; q < 4; ++q) {
        const int i = i0 + q;
        wq[q] = (i < cn) ? wbuf[(size_t)(c0 + i) * 128 + wi] : 0.f;
      }
#pragma unroll
      for (int q = 0; q < 4; ++q) {
        const int i = i0 + q;
        if (i < cn) {
          const float* yr = yL[i];
          const float A = eaL[i][selA];
          if (is1) {
            accv += wq[q] * (A * yr[yi0] + eaL[i][2] * yr[yi1] + eaL[i][3] * yr[yi2]);
          } else {
            accv += wq[q] * (A * yr[yi0]);
          }
        }
      }
    }
    __syncthreads();   // protect yL before next chunk overwrites
  }

  const float inv_sqrt3 = 0.5773502691896258f;
  if (is1) accv *= inv_sqrt3;
  sm[t] = accv;
  __syncthreads();

  const float inv_avg = rsqrtf((float)(*avgp));
  const float scl = 0.125f * inv_avg;
  if (t < 64) {
    float acc = 0.f;
    for (int u = 0; u < 64; ++u) acc += sm[u] * l2w0[u * 64 + t];
    so0[t] = acc * scl + sc[(size_t)n * 160 + t];
  } else if (t < 160) {
    const int q = t - 64, w = q / 3, i = q - w * 3;
    float acc = 0.f;
    for (int u = 0; u < 64; ++u) acc += sm[64 + u * 3 + i] * l2w1[u * 32 + w];
    so1[w * 3 + i] = acc * scl + sc[(size_t)n * 160 + 64 + w * 3 + i];
  }
  __syncthreads();
  if (t < 32) {
    out[(size_t)n * 128 + t] = nf[(size_t)n * 128 + t] + silu(so0[t]);
  } else if (t < 128) {
    const int q = t - 32, w = q / 3, i = q - w * 3;
    out[(size_t)n * 128 + t] = nf[(size_t)n * 128 + t] + silu(so0[32 + w]) * so1[w * 3 + i];
  }
}

extern "C" void kernel_launch(void* const* d_in, const int* in_sizes, int n_in,
                              void* d_out, int out_size, void* d_ws, size_t ws_size,
                              hipStream_t stream)
{
  const float* nf    = (const float*)d_in[0];
  const float* na    = (const float*)d_in[1];
  const float* eattr = (const float*)d_in[2];
  const float* eemb  = (const float*)d_in[3];
  const float* l1w0  = (const float*)d_in[4];
  const float* l1w1  = (const float*)d_in[5];
  const float* fw1   = (const float*)d_in[6];
  const float* fw2   = (const float*)d_in[7];
  const float* fw3   = (const float*)d_in[8];
  const float* l2w0  = (const float*)d_in[9];
  const float* l2w1  = (const float*)d_in[10];
  const float* scw0  = (const float*)d_in[11];
  const float* scw1  = (const float*)d_in[12];
  const int*   eidx  = (const int*)d_in[13];
  const int*   avgp  = (const int*)d_in[14];

  const int N = in_sizes[0] / 128;
  const int E = in_sizes[2] / 4;

  // Same byte layout as R3-R9 (known to fit in ws_size).
  float* y       = (float*)d_ws;                    // N*128
  float* sc      = y + (size_t)N * 128;             // N*160
  float* wbuf    = sc + (size_t)N * 160;            // E*128 (slot-major, sorted by dst)
  int*   counts  = (int*)(wbuf + (size_t)E * 128);  // N
  int*   offsets = counts + N;                      // N+1
  int*   cursor  = offsets + N + 1;                 // N
  int*   elist   = cursor + N;                      // E (slot -> eid)

  hipMemsetAsync(counts, 0, (size_t)N * sizeof(int), stream);
  node_pre_kernel<<<N, 320, 0, stream>>>(nf, na, l1w0, l1w1, scw0, scw1, y, sc);
  hist_kernel<<<(E + 255) / 256, 256, 0, stream>>>(eidx, counts, E);
  scan_kernel<<<1, 1024, 0, stream>>>(counts, offsets, cursor, N);
  scatter_kernel<<<(E + 255) / 256, 256, 0, stream>>>(eidx, cursor, elist, E);
  edge_mlp_kernel<<<(E + 127) / 128, 256, 0, stream>>>(eemb, fw1, fw2, fw3, elist, wbuf, E);
  gather_out_kernel<<<N, 256, 0, stream>>>(nf, wbuf, y, sc, l2w0, l2w1,
                                           offsets, elist, eidx, eattr, avgp,
                                           (float*)d_out, N, E);
}

// Round 12
// 336.702 us; speedup vs baseline: 1.6088x; 1.1394x over previous
//
#include <hip/hip_runtime.h>
#include <math.h>

__device__ __forceinline__ float silu(float x) { return x / (1.0f + __expf(-x)); }

typedef __attribute__((ext_vector_type(8))) short short8v;  // 8 bf16 (4 VGPRs)
typedef __attribute__((ext_vector_type(4))) float f32x4;

__device__ __forceinline__ unsigned short f2bf(float x) {
  unsigned int u = __float_as_uint(x);
  return (unsigned short)((u + 0x8000u) >> 16);   // round-half-up, fine for our range
}

// ---------------- Kernel 1: per-node precompute (R9/R11 version) -----------
__global__ __launch_bounds__(320) void node_pre_kernel(
    const float* __restrict__ nf, const float* __restrict__ na,
    const float* __restrict__ w0, const float* __restrict__ w1,
    const float* __restrict__ scw0, const float* __restrict__ scw1,
    float* __restrict__ y, float* __restrict__ sc)
{
  __shared__ float snf[128];
  __shared__ float sna[4];
  const int n = blockIdx.x;
  const int t = threadIdx.x;
  if (t < 128) snf[t] = nf[n * 128 + t];
  if (t >= 128 && t < 132) sna[t - 128] = na[n * 4 + (t - 128)];
  __syncthreads();
  const float inv_sqrt32 = 0.17677669529663687f;
  const float sc_norm    = 0.08838834764831843f;  // 1/sqrt(32*4)
  if (t < 32) {
    const int w = t;
    float acc = 0.f;
    for (int u = 0; u < 32; ++u) acc += snf[u] * w0[u * 32 + w];
    y[n * 128 + w] = acc * inv_sqrt32;
  } else if (t < 128) {
    const int q = t - 32, w = q / 3, i = q - w * 3;
    float acc = 0.f;
    for (int u = 0; u < 32; ++u) acc += snf[32 + u * 3 + i] * w1[u * 32 + w];
    y[n * 128 + 32 + w * 3 + i] = acc * inv_sqrt32;
  } else if (t < 192) {
    const int w = t - 128;
    float acc = 0.f;
    for (int k = 0; k < 128; ++k) acc += snf[k >> 2] * sna[k & 3] * scw0[k * 64 + w];
    sc[n * 160 + w] = acc * sc_norm;
  } else if (t < 288) {
    const int q = t - 192, w = q / 3, i = q - w * 3;
    float acc = 0.f;
    for (int k = 0; k < 128; ++k) acc += snf[32 + (k >> 2) * 3 + i] * sna[k & 3] * scw1[k * 32 + w];
    sc[n * 160 + 64 + w * 3 + i] = acc * sc_norm;
  }
}

// ---------------- CSR build (unchanged) ----------------
__global__ __launch_bounds__(256) void hist_kernel(const int* __restrict__ eidx,
                                                   int* __restrict__ counts, int E)
{
  const int e = blockIdx.x * 256 + threadIdx.x;
  if (e < E) atomicAdd(&counts[eidx[E + e]], 1);
}

__global__ __launch_bounds__(1024) void scan_kernel(const int* __restrict__ counts,
                                                    int* __restrict__ offsets,
                                                    int* __restrict__ cursor, int N)
{
  __shared__ int part[1024];
  const int t = threadIdx.x;
  const int per = (N + 1023) / 1024;
  const int base = t * per;
  int s = 0;
  for (int k = 0; k < per; ++k) { int idx = base + k; if (idx < N) s += counts[idx]; }
  part[t] = s;
  __syncthreads();
  for (int off = 1; off < 1024; off <<= 1) {
    int v = part[t];
    if (t >= off) v += part[t - off];
    __syncthreads();
    part[t] = v;
    __syncthreads();
  }
  int run = (t == 0) ? 0 : part[t - 1];
  for (int k = 0; k < per; ++k) {
    int idx = base + k;
    if (idx < N) { offsets[idx] = run; cursor[idx] = run; run += counts[idx]; }
  }
  if (t == 1023) offsets[N] = run;
}

__global__ __launch_bounds__(256) void scatter_kernel(const int* __restrict__ eidx,
                                                      int* __restrict__ cursor,
                                                      int* __restrict__ elist, int E)
{
  const int e = blockIdx.x * 256 + threadIdx.x;
  if (e >= E) return;
  const int dst = eidx[E + e];
  const int slot = atomicAdd(&cursor[dst], 1);
  elist[slot] = e;
}

// ---------------- Kernel 2: FUSED edge MLP; layer 3 via bf16 MFMA ----------
// Phase A: h1 f32 -> hL [k][e] (unchanged).  Phase B: h2 VALU (unchanged).
// Handoff: h2 -> bf16 LDS [e][64k] rows, 16B chunks XOR-swizzled (chunk^=(e&7)).
// w3 staged bf16-transposed [n][k] in w2L region, same swizzle.
// Phase C: 16x16x32 bf16 MFMA, 2 m-tiles x 8 n-tiles x 2 k-steps per wave.
__global__ __launch_bounds__(256) void edge_mlp_kernel(
    const float* __restrict__ eemb, const float* __restrict__ fw1,
    const float* __restrict__ fw2, const float* __restrict__ fw3,
    const int* __restrict__ elist, float* __restrict__ wbuf, int E)
{
  __shared__ __align__(16) float w1L[512];    // [k<64][r<8] transposed
  __shared__ __align__(16) float w2L[4096];   // B: w2 f32 [64][64] ; C: w3 bf16 [n=128][k=64] swz
  __shared__ __align__(16) float hL[8192];    // A/B: h1 f32 [k][e] ; C: h2 bf16 [e=128][k=64] swz
  const int t = threadIdx.x;
  const int base = blockIdx.x * 128;

  for (int x = t; x < 512; x += 256)  w1L[x] = fw1[(x & 7) * 64 + (x >> 3)];
  for (int x = t; x < 4096; x += 256) w2L[x] = fw2[x];

  // per-thread edge (2 threads per edge), emb kept in registers
  {
    const int e = t & 127, kg = t >> 7;
    const int slot0 = base + e;
    const int eid = (slot0 < E) ? elist[slot0] : 0;
    const float4 em0 = *(const float4*)(eemb + (size_t)eid * 8);
    const float4 em1 = *(const float4*)(eemb + (size_t)eid * 8 + 4);
    __syncthreads();

    // ---- phase A: h1[k][e], 32 k per thread ----
    const float inv_sqrt8 = 0.35355339059327373f;
#pragma unroll
    for (int kk = 0; kk < 32; ++kk) {
      const int k = kg * 32 + kk;
      const float4 wa = *(const float4*)(w1L + k * 8);
      const float4 wb = *(const float4*)(w1L + k * 8 + 4);
      const float a = em0.x * wa.x + em0.y * wa.y + em0.z * wa.z + em0.w * wa.w
                    + em1.x * wb.x + em1.y * wb.y + em1.z * wb.z + em1.w * wb.w;
      hL[k * 128 + e] = silu(a * inv_sqrt8);
    }
  }
  __syncthreads();

  const int og = t & 7, eg = t >> 3;
  const int e0 = eg * 4;

  // ---- phase B: h2 micro-tile 4e x 8o into registers (VALU) ----
  float acc[4][8];
#pragma unroll
  for (int i = 0; i < 4; ++i)
#pragma unroll
    for (int j = 0; j < 8; ++j) acc[i][j] = 0.f;
  {
    const int o0 = og * 8;
    for (int k = 0; k < 64; ++k) {
      const float4 hv  = *(const float4*)(hL + k * 128 + e0);
      const float4 w0v = *(const float4*)(w2L + k * 64 + o0);
      const float4 w1v = *(const float4*)(w2L + k * 64 + o0 + 4);
      const float h[4] = {hv.x, hv.y, hv.z, hv.w};
      const float w[8] = {w0v.x, w0v.y, w0v.z, w0v.w, w1v.x, w1v.y, w1v.z, w1v.w};
#pragma unroll
      for (int i = 0; i < 4; ++i)
#pragma unroll
        for (int j = 0; j < 8; ++j) acc[i][j] += h[i] * w[j];
    }
  }
  __syncthreads();   // all hL(h1)/w2L(w2) reads complete

  // ---- handoff: h2 -> bf16 [e][64] rows in hL region, chunk^=(e&7) ----
  // thread holds h2[e0..e0+3][og*8 .. og*8+7]  -> one 16B chunk per e (chunk idx = og)
#pragma unroll
  for (int i = 0; i < 4; ++i) {
    const int ee = e0 + i;
    short8v hv;
#pragma unroll
    for (int j = 0; j < 8; ++j)
      hv[j] = (short)f2bf(silu(acc[i][j] * 0.125f));
    *(short8v*)((char*)hL + ee * 128 + ((og ^ (ee & 7)) * 16)) = hv;
  }
  // ---- stage w3 bf16 transposed [n][k] into w2L region, chunk^=(n&7) ----
  for (int x = t; x < 8192; x += 256) {
    const int k = x >> 7, c = x & 127;
    ((unsigned short*)((char*)w2L + c * 128 + (((k >> 3) ^ (c & 7)) * 16)))[k & 7] = f2bf(fw3[x]);
  }
  __syncthreads();

  // ---- phase C: MFMA.  wave wv: edges [wv*32, wv*32+32), all 128 cols ----
  {
    const int wv = t >> 6, l = t & 63;
    const int lrow = l & 15, lkg = l >> 4;
    f32x4 accd[2][8];
#pragma unroll
    for (int mt = 0; mt < 2; ++mt)
#pragma unroll
      for (int nt = 0; nt < 8; ++nt)
        accd[mt][nt] = (f32x4){0.f, 0.f, 0.f, 0.f};

#pragma unroll
    for (int step = 0; step < 2; ++step) {
      const int ea0 = wv * 32 + lrow;
      const int ea1 = wv * 32 + 16 + lrow;
      const short8v A0 = *(const short8v*)((const char*)hL + ea0 * 128 + (((step * 4 + lkg) ^ (ea0 & 7)) * 16));
      const short8v A1 = *(const short8v*)((const char*)hL + ea1 * 128 + (((step * 4 + lkg) ^ (ea1 & 7)) * 16));
#pragma unroll
      for (int nt = 0; nt < 8; ++nt) {
        const int n = nt * 16 + lrow;
        const short8v B = *(const short8v*)((const char*)w2L + n * 128 + (((step * 4 + lkg) ^ (n & 7)) * 16));
        accd[0][nt] = __builtin_amdgcn_mfma_f32_16x16x32_bf16(A0, B, accd[0][nt], 0, 0, 0);
        accd[1][nt] = __builtin_amdgcn_mfma_f32_16x16x32_bf16(A1, B, accd[1][nt], 0, 0, 0);
      }
    }
    // D layout: col = lane&15, row = (lane>>4)*4 + reg  (m89-verified)
#pragma unroll
    for (int mt = 0; mt < 2; ++mt) {
#pragma unroll
      for (int r = 0; r < 4; ++r) {
        const int eo = wv * 32 + mt * 16 + lkg * 4 + r;
        const int slot = base + eo;
        if (slot < E) {
          float* wrow = wbuf + (size_t)slot * 128 + lrow;
#pragma unroll
          for (int nt = 0; nt < 8; ++nt)
            wrow[nt * 16] = accd[mt][nt][r] * 0.125f;
        }
      }
    }
  }
}

// ---------------- Kernel 3: 1 node/block, chunked cooperative staging ------
__global__ __launch_bounds__(256) void gather_out_kernel(
    const float* __restrict__ nf, const float* __restrict__ wbuf,
    const float* __restrict__ y, const float* __restrict__ sc,
    const float* __restrict__ l2w0, const float* __restrict__ l2w1,
    const int* __restrict__ offsets, const int* __restrict__ elist,
    const int* __restrict__ eidx, const float* __restrict__ eattr,
    const int* __restrict__ avgp, float* __restrict__ out, int N, int E)
{
  constexpr int CH = 32;
  __shared__ int sSrc[CH];
  __shared__ __align__(16) float eaL[CH][4];
  __shared__ __align__(16) float yL[CH][128];
  __shared__ float sm[256];
  __shared__ float so0[64];
  __shared__ float so1[96];
  const int n = blockIdx.x, t = threadIdx.x;

  int wi, yi0, yi1, yi2, selA;  // selA: 0=e0,1=e1x,2=e1y,3=e1z
  bool is1 = false;
  if (t < 32) {            // o_s0[u]
    wi = t; yi0 = yi1 = yi2 = t; selA = 0;
  } else if (t < 64) {     // o_s1[u]
    const int u = t - 32;
    wi = 96 + u; yi0 = 32 + 3 * u; yi1 = yi0 + 1; yi2 = yi0 + 2; selA = 1; is1 = true;
  } else if (t < 160) {    // o_v0[u][i]
    const int q = t - 64, u = q / 3, i = q - u * 3;
    wi = 32 + u; yi0 = yi1 = yi2 = u; selA = 1 + i;
  } else {                 // o_v1[u][i]
    const int q = t - 160, u = q / 3, i = q - u * 3;
    wi = 64 + u; yi0 = yi1 = yi2 = 32 + 3 * u + i; selA = 0;
  }

  const int beg = offsets[n], end = offsets[n + 1];
  float accv = 0.f;

  for (int c0 = beg; c0 < end; c0 += CH) {
    const int cn = min(CH, end - c0);
    if (t < CH) {
      int srcv = 0;
      float4 eav = make_float4(0.f, 0.f, 0.f, 0.f);
      if (t < cn) {
        const int eid = elist[c0 + t];
        srcv = eidx[eid];
        eav = *(const float4*)(eattr + (size_t)eid * 4);
      }
      sSrc[t] = srcv;
      *(float4*)&eaL[t][0] = eav;
    }
    __syncthreads();
#pragma unroll
    for (int p = 0; p < 4; ++p) {
      const int lin = p * 256 + t;          // float4 index
      const int row = lin >> 5, f4 = lin & 31;
      if (row < cn) {
        *(float4*)&yL[row][f4 * 4] =
            *(const float4*)(y + (size_t)sSrc[row] * 128 + f4 * 4);
      }
    }
    __syncthreads();
    for (int i0 = 0; i0 < cn; i0 += 4) {
      float wq[4];
#pragma unroll
      for (int q = 0; q < 4; ++q) {
        const int i = i0 + q;
        wq[q] = (i < cn) ? wbuf[(size_t)(c0 + i) * 128 + wi] : 0.f;
      }
#pragma unroll
      for (int q = 0; q < 4; ++q) {
        const int i = i0 + q;
        if (i < cn) {
          const float* yr = yL[i];
          const float A = eaL[i][selA];
          if (is1) {
            accv += wq[q] * (A * yr[yi0] + eaL[i][2] * yr[yi1] + eaL[i][3] * yr[yi2]);
          } else {
            accv += wq[q] * (A * yr[yi0]);
          }
        }
      }
    }
    __syncthreads();   // protect yL before next chunk overwrites
  }

  const float inv_sqrt3 = 0.5773502691896258f;
  if (is1) accv *= inv_sqrt3;
  sm[t] = accv;
  __syncthreads();

  const float inv_avg = rsqrtf((float)(*avgp));
  const float scl = 0.125f * inv_avg;
  if (t < 64) {
    float acc = 0.f;
    for (int u = 0; u < 64; ++u) acc += sm[u] * l2w0[u * 64 + t];
    so0[t] = acc * scl + sc[(size_t)n * 160 + t];
  } else if (t < 160) {
    const int q = t - 64, w = q / 3, i = q - w * 3;
    float acc = 0.f;
    for (int u = 0; u < 64; ++u) acc += sm[64 + u * 3 + i] * l2w1[u * 32 + w];
    so1[w * 3 + i] = acc * scl + sc[(size_t)n * 160 + 64 + w * 3 + i];
  }
  __syncthreads();
  if (t < 32) {
    out[(size_t)n * 128 + t] = nf[(size_t)n * 128 + t] + silu(so0[t]);
  } else if (t < 128) {
    const int q = t - 32, w = q / 3, i = q - w * 3;
    out[(size_t)n * 128 + t] = nf[(size_t)n * 128 + t] + silu(so0[32 + w]) * so1[w * 3 + i];
  }
}

extern "C" void kernel_launch(void* const* d_in, const int* in_sizes, int n_in,
                              void* d_out, int out_size, void* d_ws, size_t ws_size,
                              hipStream_t stream)
{
  const float* nf    = (const float*)d_in[0];
  const float* na    = (const float*)d_in[1];
  const float* eattr = (const float*)d_in[2];
  const float* eemb  = (const float*)d_in[3];
  const float* l1w0  = (const float*)d_in[4];
  const float* l1w1  = (const float*)d_in[5];
  const float* fw1   = (const float*)d_in[6];
  const float* fw2   = (const float*)d_in[7];
  const float* fw3   = (const float*)d_in[8];
  const float* l2w0  = (const float*)d_in[9];
  const float* l2w1  = (const float*)d_in[10];
  const float* scw0  = (const float*)d_in[11];
  const float* scw1  = (const float*)d_in[12];
  const int*   eidx  = (const int*)d_in[13];
  const int*   avgp  = (const int*)d_in[14];

  const int N = in_sizes[0] / 128;
  const int E = in_sizes[2] / 4;

  // Same byte layout as R3-R11 (known to fit in ws_size).
  float* y       = (float*)d_ws;                    // N*128
  float* sc      = y + (size_t)N * 128;             // N*160
  float* wbuf    = sc + (size_t)N * 160;            // E*128 (slot-major, sorted by dst)
  int*   counts  = (int*)(wbuf + (size_t)E * 128);  // N
  int*   offsets = counts + N;                      // N+1
  int*   cursor  = offsets + N + 1;                 // N
  int*   elist   = cursor + N;                      // E (slot -> eid)

  hipMemsetAsync(counts, 0, (size_t)N * sizeof(int), stream);
  node_pre_kernel<<<N, 320, 0, stream>>>(nf, na, l1w0, l1w1, scw0, scw1, y, sc);
  hist_kernel<<<(E + 255) / 256, 256, 0, stream>>>(eidx, counts, E);
  scan_kernel<<<1, 1024, 0, stream>>>(counts, offsets, cursor, N);
  scatter_kernel<<<(E + 255) / 256, 256, 0, stream>>>(eidx, cursor, elist, E);
  edge_mlp_kernel<<<(E + 127) / 128, 256, 0, stream>>>(eemb, fw1, fw2, fw3, elist, wbuf, E);
  gather_out_kernel<<<N, 256, 0, stream>>>(nf, wbuf, y, sc, l2w0, l2w1,
                                           offsets, elist, eidx, eattr, avgp,
                                           (float*)d_out, N, E);
}

// Round 13
// 320.983 us; speedup vs baseline: 1.6876x; 1.0490x over previous
//
#include <hip/hip_runtime.h>
#include <math.h>

__device__ __forceinline__ float silu(float x) { return x / (1.0f + __expf(-x)); }

typedef __attribute__((ext_vector_type(8))) short short8v;  // 8 bf16 (4 VGPRs)
typedef __attribute__((ext_vector_type(4))) float f32x4;

__device__ __forceinline__ unsigned short f2bf(float x) {
  unsigned int u = __float_as_uint(x);
  return (unsigned short)((u + 0x8000u) >> 16);
}

// ---------------- Kernel 1: per-node precompute (R9/R11 version) -----------
__global__ __launch_bounds__(320) void node_pre_kernel(
    const float* __restrict__ nf, const float* __restrict__ na,
    const float* __restrict__ w0, const float* __restrict__ w1,
    const float* __restrict__ scw0, const float* __restrict__ scw1,
    float* __restrict__ y, float* __restrict__ sc)
{
  __shared__ float snf[128];
  __shared__ float sna[4];
  const int n = blockIdx.x;
  const int t = threadIdx.x;
  if (t < 128) snf[t] = nf[n * 128 + t];
  if (t >= 128 && t < 132) sna[t - 128] = na[n * 4 + (t - 128)];
  __syncthreads();
  const float inv_sqrt32 = 0.17677669529663687f;
  const float sc_norm    = 0.08838834764831843f;  // 1/sqrt(32*4)
  if (t < 32) {
    const int w = t;
    float acc = 0.f;
    for (int u = 0; u < 32; ++u) acc += snf[u] * w0[u * 32 + w];
    y[n * 128 + w] = acc * inv_sqrt32;
  } else if (t < 128) {
    const int q = t - 32, w = q / 3, i = q - w * 3;
    float acc = 0.f;
    for (int u = 0; u < 32; ++u) acc += snf[32 + u * 3 + i] * w1[u * 32 + w];
    y[n * 128 + 32 + w * 3 + i] = acc * inv_sqrt32;
  } else if (t < 192) {
    const int w = t - 128;
    float acc = 0.f;
    for (int k = 0; k < 128; ++k) acc += snf[k >> 2] * sna[k & 3] * scw0[k * 64 + w];
    sc[n * 160 + w] = acc * sc_norm;
  } else if (t < 288) {
    const int q = t - 192, w = q / 3, i = q - w * 3;
    float acc = 0.f;
    for (int k = 0; k < 128; ++k) acc += snf[32 + (k >> 2) * 3 + i] * sna[k & 3] * scw1[k * 32 + w];
    sc[n * 160 + 64 + w * 3 + i] = acc * sc_norm;
  }
}

// ---------------- CSR build (unchanged) ----------------
__global__ __launch_bounds__(256) void hist_kernel(const int* __restrict__ eidx,
                                                   int* __restrict__ counts, int E)
{
  const int e = blockIdx.x * 256 + threadIdx.x;
  if (e < E) atomicAdd(&counts[eidx[E + e]], 1);
}

__global__ __launch_bounds__(1024) void scan_kernel(const int* __restrict__ counts,
                                                    int* __restrict__ offsets,
                                                    int* __restrict__ cursor, int N)
{
  __shared__ int part[1024];
  const int t = threadIdx.x;
  const int per = (N + 1023) / 1024;
  const int base = t * per;
  int s = 0;
  for (int k = 0; k < per; ++k) { int idx = base + k; if (idx < N) s += counts[idx]; }
  part[t] = s;
  __syncthreads();
  for (int off = 1; off < 1024; off <<= 1) {
    int v = part[t];
    if (t >= off) v += part[t - off];
    __syncthreads();
    part[t] = v;
    __syncthreads();
  }
  int run = (t == 0) ? 0 : part[t - 1];
  for (int k = 0; k < per; ++k) {
    int idx = base + k;
    if (idx < N) { offsets[idx] = run; cursor[idx] = run; run += counts[idx]; }
  }
  if (t == 1023) offsets[N] = run;
}

__global__ __launch_bounds__(256) void scatter_kernel(const int* __restrict__ eidx,
                                                      int* __restrict__ cursor,
                                                      int* __restrict__ elist, int E)
{
  const int e = blockIdx.x * 256 + threadIdx.x;
  if (e >= E) return;
  const int dst = eidx[E + e];
  const int slot = atomicAdd(&cursor[dst], 1);
  elist[slot] = e;
}

// ---------------- Kernel 2: FUSED edge MLP; layer 3 via bf16 MFMA (R12) ----
__global__ __launch_bounds__(256) void edge_mlp_kernel(
    const float* __restrict__ eemb, const float* __restrict__ fw1,
    const float* __restrict__ fw2, const float* __restrict__ fw3,
    const int* __restrict__ elist, float* __restrict__ wbuf, int E)
{
  __shared__ __align__(16) float w1L[512];    // [k<64][r<8] transposed
  __shared__ __align__(16) float w2L[4096];   // B: w2 f32 ; C: w3 bf16 [n][k] swz
  __shared__ __align__(16) float hL[8192];    // A/B: h1 f32 [k][e] ; C: h2 bf16 [e][k] swz
  const int t = threadIdx.x;
  const int base = blockIdx.x * 128;

  for (int x = t; x < 512; x += 256)  w1L[x] = fw1[(x & 7) * 64 + (x >> 3)];
  for (int x = t; x < 4096; x += 256) w2L[x] = fw2[x];

  {
    const int e = t & 127, kg = t >> 7;
    const int slot0 = base + e;
    const int eid = (slot0 < E) ? elist[slot0] : 0;
    const float4 em0 = *(const float4*)(eemb + (size_t)eid * 8);
    const float4 em1 = *(const float4*)(eemb + (size_t)eid * 8 + 4);
    __syncthreads();

    const float inv_sqrt8 = 0.35355339059327373f;
#pragma unroll
    for (int kk = 0; kk < 32; ++kk) {
      const int k = kg * 32 + kk;
      const float4 wa = *(const float4*)(w1L + k * 8);
      const float4 wb = *(const float4*)(w1L + k * 8 + 4);
      const float a = em0.x * wa.x + em0.y * wa.y + em0.z * wa.z + em0.w * wa.w
                    + em1.x * wb.x + em1.y * wb.y + em1.z * wb.z + em1.w * wb.w;
      hL[k * 128 + e] = silu(a * inv_sqrt8);
    }
  }
  __syncthreads();

  const int og = t & 7, eg = t >> 3;
  const int e0 = eg * 4;

  float acc[4][8];
#pragma unroll
  for (int i = 0; i < 4; ++i)
#pragma unroll
    for (int j = 0; j < 8; ++j) acc[i][j] = 0.f;
  {
    const int o0 = og * 8;
    for (int k = 0; k < 64; ++k) {
      const float4 hv  = *(const float4*)(hL + k * 128 + e0);
      const float4 w0v = *(const float4*)(w2L + k * 64 + o0);
      const float4 w1v = *(const float4*)(w2L + k * 64 + o0 + 4);
      const float h[4] = {hv.x, hv.y, hv.z, hv.w};
      const float w[8] = {w0v.x, w0v.y, w0v.z, w0v.w, w1v.x, w1v.y, w1v.z, w1v.w};
#pragma unroll
      for (int i = 0; i < 4; ++i)
#pragma unroll
        for (int j = 0; j < 8; ++j) acc[i][j] += h[i] * w[j];
    }
  }
  __syncthreads();

#pragma unroll
  for (int i = 0; i < 4; ++i) {
    const int ee = e0 + i;
    short8v hv;
#pragma unroll
    for (int j = 0; j < 8; ++j)
      hv[j] = (short)f2bf(silu(acc[i][j] * 0.125f));
    *(short8v*)((char*)hL + ee * 128 + ((og ^ (ee & 7)) * 16)) = hv;
  }
  for (int x = t; x < 8192; x += 256) {
    const int k = x >> 7, c = x & 127;
    ((unsigned short*)((char*)w2L + c * 128 + (((k >> 3) ^ (c & 7)) * 16)))[k & 7] = f2bf(fw3[x]);
  }
  __syncthreads();

  {
    const int wv = t >> 6, l = t & 63;
    const int lrow = l & 15, lkg = l >> 4;
    f32x4 accd[2][8];
#pragma unroll
    for (int mt = 0; mt < 2; ++mt)
#pragma unroll
      for (int nt = 0; nt < 8; ++nt)
        accd[mt][nt] = (f32x4){0.f, 0.f, 0.f, 0.f};

#pragma unroll
    for (int step = 0; step < 2; ++step) {
      const int ea0 = wv * 32 + lrow;
      const int ea1 = wv * 32 + 16 + lrow;
      const short8v A0 = *(const short8v*)((const char*)hL + ea0 * 128 + (((step * 4 + lkg) ^ (ea0 & 7)) * 16));
      const short8v A1 = *(const short8v*)((const char*)hL + ea1 * 128 + (((step * 4 + lkg) ^ (ea1 & 7)) * 16));
#pragma unroll
      for (int nt = 0; nt < 8; ++nt) {
        const int n = nt * 16 + lrow;
        const short8v B = *(const short8v*)((const char*)w2L + n * 128 + (((step * 4 + lkg) ^ (n & 7)) * 16));
        accd[0][nt] = __builtin_amdgcn_mfma_f32_16x16x32_bf16(A0, B, accd[0][nt], 0, 0, 0);
        accd[1][nt] = __builtin_amdgcn_mfma_f32_16x16x32_bf16(A1, B, accd[1][nt], 0, 0, 0);
      }
    }
#pragma unroll
    for (int mt = 0; mt < 2; ++mt) {
#pragma unroll
      for (int r = 0; r < 4; ++r) {
        const int eo = wv * 32 + mt * 16 + lkg * 4 + r;
        const int slot = base + eo;
        if (slot < E) {
          float* wrow = wbuf + (size_t)slot * 128 + lrow;
#pragma unroll
          for (int nt = 0; nt < 8; ++nt)
            wrow[nt * 16] = accd[mt][nt][r] * 0.125f;
        }
      }
    }
  }
}

// ---------------- Kernel 3: wave-per-node gather + epilogue ----------------
// Lane = (u = l&31, half = l>>5); 8 accumulators per lane; halves split slots.
// No barriers in the gather loop; 2 block barriers total for the epilogue.
__global__ __launch_bounds__(256) void gather_out_kernel(
    const float* __restrict__ nf, const float* __restrict__ wbuf,
    const float* __restrict__ y, const float* __restrict__ sc,
    const float* __restrict__ l2w0, const float* __restrict__ l2w1,
    const int* __restrict__ offsets, const int* __restrict__ elist,
    const int* __restrict__ eidx, const float* __restrict__ eattr,
    const int* __restrict__ avgp, float* __restrict__ out, int N, int E)
{
  __shared__ float mW[4][264];    // per-wave m[256] (+pad)
  __shared__ float soW[4][160];   // per-wave so0[64] + so1[96]
  const int t = threadIdx.x;
  const int wv = t >> 6, l = t & 63;
  const int n = blockIdx.x * 4 + wv;
  const bool valid = (n < N);
  const int u = l & 31, half = l >> 5;

  const int beg = valid ? offsets[n] : 0;
  const int end = valid ? offsets[n + 1] : 0;

  float s0 = 0.f, s1 = 0.f;
  float v0x = 0.f, v0y = 0.f, v0z = 0.f;
  float v1x = 0.f, v1y = 0.f, v1z = 0.f;

  for (int s = beg + half; s < end; s += 2) {
    const int eid = elist[s];
    const int src = eidx[eid];
    const float4 ea = *(const float4*)(eattr + (size_t)eid * 4);
    const float* wr = wbuf + (size_t)s * 128;
    const float* yr = y + (size_t)src * 128;
    const float w00 = wr[u], w01 = wr[32 + u], w10 = wr[64 + u], w11 = wr[96 + u];
    const float g0  = yr[u];
    const float g1x = yr[32 + 3 * u], g1y = yr[33 + 3 * u], g1z = yr[34 + 3 * u];
    s0 += w00 * g0 * ea.x;
    const float t01 = w01 * g0;
    v0x += t01 * ea.y; v0y += t01 * ea.z; v0z += t01 * ea.w;
    const float wg = w10 * ea.x;
    v1x += wg * g1x; v1y += wg * g1y; v1z += wg * g1z;
    s1 += w11 * (g1x * ea.y + g1y * ea.z + g1z * ea.w);
  }
  // combine halves
  s0 += __shfl_xor(s0, 32);  s1 += __shfl_xor(s1, 32);
  v0x += __shfl_xor(v0x, 32); v0y += __shfl_xor(v0y, 32); v0z += __shfl_xor(v0z, 32);
  v1x += __shfl_xor(v1x, 32); v1y += __shfl_xor(v1y, 32); v1z += __shfl_xor(v1z, 32);
  if (half == 0) {
    mW[wv][u]          = s0;
    mW[wv][32 + u]     = s1 * 0.5773502691896258f;
    mW[wv][64 + 3 * u] = v0x; mW[wv][65 + 3 * u] = v0y; mW[wv][66 + 3 * u] = v0z;
    mW[wv][160 + 3 * u] = v1x; mW[wv][161 + 3 * u] = v1y; mW[wv][162 + 3 * u] = v1z;
  }
  __syncthreads();

  const float scl = 0.125f * rsqrtf((float)(*avgp));
  const float* m = mW[wv];
  if (valid) {
    // so0[l]: dot(m[0:64], l2w0[:,l])
    {
      float acc = 0.f;
      for (int uu = 0; uu < 64; ++uu) acc += m[uu] * l2w0[uu * 64 + l];
      soW[wv][l] = acc * scl + sc[(size_t)n * 160 + l];
    }
    // so1[q], q = l (0..63)
    {
      const int w = l / 3, i = l - 3 * w;
      float acc = 0.f;
      for (int uu = 0; uu < 64; ++uu) acc += m[64 + uu * 3 + i] * l2w1[uu * 32 + w];
      soW[wv][64 + l] = acc * scl + sc[(size_t)n * 160 + 64 + l];
    }
    // so1[q], q = 64 + l (l < 32)
    if (l < 32) {
      const int q = 64 + l, w = q / 3, i = q - 3 * w;
      float acc = 0.f;
      for (int uu = 0; uu < 64; ++uu) acc += m[64 + uu * 3 + i] * l2w1[uu * 32 + w];
      soW[wv][64 + q] = acc * scl + sc[(size_t)n * 160 + 64 + q];
    }
  }
  __syncthreads();

  if (valid) {
#pragma unroll
    for (int p = 0; p < 2; ++p) {
      const int c = p * 64 + l;
      float val;
      if (c < 32) {
        val = silu(soW[wv][c]);
      } else {
        const int q = c - 32, w = q / 3, i = q - 3 * w;
        val = silu(soW[wv][32 + w]) * soW[wv][64 + w * 3 + i];
      }
      out[(size_t)n * 128 + c] = nf[(size_t)n * 128 + c] + val;
    }
  }
}

extern "C" void kernel_launch(void* const* d_in, const int* in_sizes, int n_in,
                              void* d_out, int out_size, void* d_ws, size_t ws_size,
                              hipStream_t stream)
{
  const float* nf    = (const float*)d_in[0];
  const float* na    = (const float*)d_in[1];
  const float* eattr = (const float*)d_in[2];
  const float* eemb  = (const float*)d_in[3];
  const float* l1w0  = (const float*)d_in[4];
  const float* l1w1  = (const float*)d_in[5];
  const float* fw1   = (const float*)d_in[6];
  const float* fw2   = (const float*)d_in[7];
  const float* fw3   = (const float*)d_in[8];
  const float* l2w0  = (const float*)d_in[9];
  const float* l2w1  = (const float*)d_in[10];
  const float* scw0  = (const float*)d_in[11];
  const float* scw1  = (const float*)d_in[12];
  const int*   eidx  = (const int*)d_in[13];
  const int*   avgp  = (const int*)d_in[14];

  const int N = in_sizes[0] / 128;
  const int E = in_sizes[2] / 4;

  // Same byte layout as R3-R12 (known to fit in ws_size).
  float* y       = (float*)d_ws;                    // N*128
  float* sc      = y + (size_t)N * 128;             // N*160
  float* wbuf    = sc + (size_t)N * 160;            // E*128 (slot-major, sorted by dst)
  int*   counts  = (int*)(wbuf + (size_t)E * 128);  // N
  int*   offsets = counts + N;                      // N+1
  int*   cursor  = offsets + N + 1;                 // N
  int*   elist   = cursor + N;                      // E (slot -> eid)

  hipMemsetAsync(counts, 0, (size_t)N * sizeof(int), stream);
  node_pre_kernel<<<N, 320, 0, stream>>>(nf, na, l1w0, l1w1, scw0, scw1, y, sc);
  hist_kernel<<<(E + 255) / 256, 256, 0, stream>>>(eidx, counts, E);
  scan_kernel<<<1, 1024, 0, stream>>>(counts, offsets, cursor, N);
  scatter_kernel<<<(E + 255) / 256, 256, 0, stream>>>(eidx, cursor, elist, E);
  edge_mlp_kernel<<<(E + 127) / 128, 256, 0, stream>>>(eemb, fw1, fw2, fw3, elist, wbuf, E);
  gather_out_kernel<<<(N + 3) / 4, 256, 0, stream>>>(nf, wbuf, y, sc, l2w0, l2w1,
                                                     offsets, elist, eidx, eattr, avgp,
                                                     (float*)d_out, N, E);
}